// Round 8
// baseline (287.386 us; speedup 1.0000x reference)
//
#include <hip/hip_runtime.h>
#include <hip/hip_bf16.h>
#include <stdint.h>

#define B_N 16384
#define F_N 1024
#define D_N 4
#define O_N 32
#define NCOL1 (D_N * F_N) /* 4096 */
#define NCOL2 (D_N * O_N) /* 128  */

static constexpr float EPS = 1e-5f;

typedef __bf16 bf16x8 __attribute__((ext_vector_type(8)));
typedef __bf16 bf16x4 __attribute__((ext_vector_type(4)));
typedef float  f32x4  __attribute__((ext_vector_type(4)));

// global -> LDS async copy, 16B per lane. LDS dest must be wave-uniform base.
#define GLD16(gp, lp)                                                          \
  __builtin_amdgcn_global_load_lds(                                            \
      (__attribute__((address_space(1))) void*)(uintptr_t)(gp),                \
      (__attribute__((address_space(3))) void*)(lp), 16, 0, 0)

// ---------------- fused: BN1 stats + x->bf16 convert  |  fold W2 ----------
// blocks [0,512): stats+convert over 32 rows each; blocks [512,640): W2->bf16.
__global__ __launch_bounds__(256) void k_pre(
    const float* __restrict__ x, float* __restrict__ part,
    __bf16* __restrict__ xb, const float* __restrict__ W2,
    __bf16* __restrict__ W2b) {
  int t = threadIdx.x, blk = blockIdx.x;
  if (blk < 512) {
    const float4* xr = (const float4*)x;
    float s0 = 0, s1 = 0, s2 = 0, s3 = 0, q0 = 0, q1 = 0, q2 = 0, q3 = 0;
    int r0 = blk * 32;
    for (int r = r0; r < r0 + 32; ++r) {
      float4 v = xr[(size_t)r * (F_N / 4) + t];
      s0 += v.x; q0 += v.x * v.x;
      s1 += v.y; q1 += v.y * v.y;
      s2 += v.z; q2 += v.z * v.z;
      s3 += v.w; q3 += v.w * v.w;
      bf16x4 o;
      o[0] = (__bf16)v.x; o[1] = (__bf16)v.y; o[2] = (__bf16)v.z; o[3] = (__bf16)v.w;
      *(bf16x4*)(xb + (size_t)r * F_N + t * 4) = o;
    }
    float* p = part + (size_t)blk * 2048;
    p[t * 4 + 0] = s0; p[t * 4 + 1] = s1; p[t * 4 + 2] = s2; p[t * 4 + 3] = s3;
    p[1024 + t * 4 + 0] = q0; p[1024 + t * 4 + 1] = q1;
    p[1024 + t * 4 + 2] = q2; p[1024 + t * 4 + 3] = q3;
  } else {
    size_t base = (size_t)((blk - 512) * 256 + t) * 4;
    float4 w = *(const float4*)(W2 + base);
    bf16x4 o;
    o[0] = (__bf16)w.x; o[1] = (__bf16)w.y; o[2] = (__bf16)w.z; o[3] = (__bf16)w.w;
    *(bf16x4*)(W2b + base) = o;
  }
}

__global__ __launch_bounds__(256) void k_stats_x_final(
    const float* __restrict__ part, float* __restrict__ rstdx) {
  int c = blockIdx.x * 256 + threadIdx.x;
  float s = 0, q = 0;
  for (int b = 0; b < 512; ++b) {
    s += part[(size_t)b * 2048 + c];
    q += part[(size_t)b * 2048 + 1024 + c];
  }
  float mean = s * (1.0f / B_N);
  float var = q * (1.0f / B_N) - mean * mean;
  rstdx[c] = rsqrtf(var + EPS);
}

// ---------------- fold g1 * rstd1 into W1, convert to bf16 ----------------
__global__ __launch_bounds__(256) void k_fold_w1(const float* __restrict__ W1,
                                                 const float* __restrict__ g1,
                                                 const float* __restrict__ rstdx,
                                                 __bf16* __restrict__ W1b) {
  size_t base = (size_t)(blockIdx.x * 256 + threadIdx.x) * 4;
  int f = (int)(base & (F_N - 1));
  int d = (int)(base >> 20);
  float4 w = *(const float4*)(W1 + base);
  float4 g = *(const float4*)(g1 + d * F_N + f);
  float4 r = *(const float4*)(rstdx + f);
  bf16x4 o;
  o[0] = (__bf16)(w.x * g.x * r.x); o[1] = (__bf16)(w.y * g.y * r.y);
  o[2] = (__bf16)(w.z * g.z * r.z); o[3] = (__bf16)(w.w * g.w * r.w);
  *(bf16x4*)(W1b + base) = o;
}

// ---------------- GEMM1: G1[16384][4096] = xb @ W1b^T, 256^2 pipelined -----
// (r4 winner, verbatim) BM=BN=256, BK=64, 8 waves, 128 KiB LDS, swizzled
// slots, XCD remap, 1-phase register pipeline (E/O frag sets), counted
// vmcnt(4) at phases 2 & 4. Epilogue: C write + BN2 column partial sums.
__global__ __launch_bounds__(512, 2) void k_gemm1(
    const __bf16* __restrict__ A, const __bf16* __restrict__ Bw,
    __bf16* __restrict__ C, float* __restrict__ p2s, float* __restrict__ p2q) {
  __shared__ __bf16 ldsA[2][2][256 * 32];
  __shared__ __bf16 ldsB[2][2][256 * 32];
  const int tid = threadIdx.x;
  const int wave = tid >> 6, lane = tid & 63;
  const int wm = wave >> 2, wn = wave & 3;
  int bid = (int)blockIdx.x;
  const int c_ = bid & 7, q_ = bid >> 3;
  const int bm = c_ * 8 + (q_ >> 4), bn = q_ & 15;
  const int m0 = bm * 256, n0 = bn * 256;
  const int fr = lane & 15, kg = lane >> 4;
  const int swz8 = (kg ^ ((fr >> 1) & 3)) * 8;
  const int srow = tid >> 2;
  const int scb = ((tid & 3) ^ ((tid >> 3) & 3)) * 16;
  const char* Ab = (const char*)A + (size_t)(m0 + srow) * (F_N * 2) + scb;
  const char* Bb = (const char*)Bw + (size_t)(n0 + srow) * (F_N * 2) + scb;
  char* ldsAx = (char*)&ldsA[0][0][0];
  char* ldsBx = (char*)&ldsB[0][0][0];
  const int wo = wave * 1024;

#define SA(buf_, kk_, kb_)                                                     \
  do {                                                                         \
    GLD16(Ab + (kb_) + (kk_) * 64,                                             \
          ldsAx + (buf_) * 32768 + (kk_) * 16384 + wo);                        \
    GLD16(Ab + 128 * (F_N * 2) + (kb_) + (kk_) * 64,                           \
          ldsAx + (buf_) * 32768 + (kk_) * 16384 + 8192 + wo);                 \
  } while (0)
#define SBv(buf_, kk_, kb_)                                                    \
  do {                                                                         \
    GLD16(Bb + (kb_) + (kk_) * 64,                                             \
          ldsBx + (buf_) * 32768 + (kk_) * 16384 + wo);                        \
    GLD16(Bb + 128 * (F_N * 2) + (kb_) + (kk_) * 64,                           \
          ldsBx + (buf_) * 32768 + (kk_) * 16384 + 8192 + wo);                 \
  } while (0)
#define LDA4(dst_, buf_, kk_, qm_)                                             \
  { _Pragma("unroll") for (int i_ = 0; i_ < 4; ++i_)                           \
      dst_[i_] = *(const bf16x8*)&ldsA[buf_][kk_]                              \
          [(wm * 128 + (qm_) * 64 + i_ * 16 + fr) * 32 + swz8]; }
#define LDB4(dst_, buf_, kk_)                                                  \
  { _Pragma("unroll") for (int i_ = 0; i_ < 4; ++i_)                           \
      dst_[i_] = *(const bf16x8*)&ldsB[buf_][kk_]                              \
          [(wn * 64 + i_ * 16 + fr) * 32 + swz8]; }
#define MFMA16(a_, b_, qm_)                                                    \
  { _Pragma("unroll") for (int i_ = 0; i_ < 4; ++i_)                           \
      _Pragma("unroll") for (int j_ = 0; j_ < 4; ++j_)                         \
        acc[(qm_) * 4 + i_][j_] = __builtin_amdgcn_mfma_f32_16x16x32_bf16(     \
            a_[i_], b_[j_], acc[(qm_) * 4 + i_][j_], 0, 0, 0); }
#define BAR() __builtin_amdgcn_s_barrier()
#define SB0() __builtin_amdgcn_sched_barrier(0)
#define WAITVM4() asm volatile("s_waitcnt vmcnt(4)" ::: "memory")
#define PRIO1() __builtin_amdgcn_s_setprio(1)
#define PRIO0() __builtin_amdgcn_s_setprio(0)

  f32x4 acc[8][4] = {};
  bf16x8 afrE[4], afrO[4], bfrE[4], bfrO[4];

  SBv(0, 0, 0); SA(0, 0, 0); SBv(0, 1, 0); SA(0, 1, 0);
  asm volatile("s_waitcnt vmcnt(4)" ::: "memory");
  BAR(); SB0();
  LDA4(afrE, 0, 0, 0); LDB4(bfrE, 0, 0);

#define TILE(b_, nb_, kn_)                                                     \
  SBv(nb_, 0, kn_); BAR(); SB0();                                              \
  LDA4(afrO, b_, 0, 1);                                                        \
  PRIO1(); MFMA16(afrE, bfrE, 0); PRIO0();                                     \
  SA(nb_, 0, kn_); WAITVM4(); BAR(); SB0();                                    \
  LDA4(afrE, b_, 1, 0); LDB4(bfrO, b_, 1);                                     \
  PRIO1(); MFMA16(afrO, bfrE, 1); PRIO0();                                     \
  SBv(nb_, 1, kn_); BAR(); SB0();                                              \
  LDA4(afrO, b_, 1, 1);                                                        \
  PRIO1(); MFMA16(afrE, bfrO, 0); PRIO0();                                     \
  SA(nb_, 1, kn_); WAITVM4(); BAR(); SB0();                                    \
  LDA4(afrE, nb_, 0, 0); LDB4(bfrE, nb_, 0);                                   \
  PRIO1(); MFMA16(afrO, bfrO, 1); PRIO0();

  for (int t = 0; t < 16; t += 2) {
    const int kn1 = (t + 1) * 128;
    const int kn2 = (t + 2 < 16) ? (t + 2) * 128 : 0;  // tail wraps (harmless)
    TILE(0, 1, kn1)
    TILE(1, 0, kn2)
  }

  // ---- epilogue: C write ----
  const int cr = kg * 4, cc = fr;
#pragma unroll
  for (int mi = 0; mi < 8; ++mi)
#pragma unroll
    for (int ni = 0; ni < 4; ++ni) {
      int row = m0 + wm * 128 + mi * 16 + cr;
      int col = n0 + wn * 64 + ni * 16 + cc;
#pragma unroll
      for (int r = 0; r < 4; ++r)
        C[(size_t)(row + r) * NCOL1 + col] = (__bf16)acc[mi][ni][r];
    }

  // ---- epilogue: BN2 per-block column partial sums (from f32 acc) ----
  float* srs = (float*)&ldsA[1][0][0];
  float* srq = srs + 512;
  __syncthreads();
#pragma unroll
  for (int ni = 0; ni < 4; ++ni) {
    float ss = 0, qq = 0;
#pragma unroll
    for (int mi = 0; mi < 8; ++mi) {
      f32x4 v = acc[mi][ni];
#pragma unroll
      for (int r = 0; r < 4; ++r) { ss += v[r]; qq += v[r] * v[r]; }
    }
    ss += __shfl_xor(ss, 16); ss += __shfl_xor(ss, 32);
    qq += __shfl_xor(qq, 16); qq += __shfl_xor(qq, 32);
    if (lane < 16) {
      srs[wave * 64 + ni * 16 + lane] = ss;
      srq[wave * 64 + ni * 16 + lane] = qq;
    }
  }
  __syncthreads();
  if (tid < 256) {
    int j = tid, wnn = j >> 6, jj = j & 63;
    float S = srs[wnn * 64 + jj] + srs[(4 + wnn) * 64 + jj];
    float Q = srq[wnn * 64 + jj] + srq[(4 + wnn) * 64 + jj];
    p2s[(size_t)bm * NCOL1 + n0 + j] = S;
    p2q[(size_t)bm * NCOL1 + n0 + j] = Q;
  }
#undef SA
#undef SBv
#undef LDA4
#undef LDB4
#undef MFMA16
#undef TILE
#undef BAR
#undef SB0
#undef WAITVM4
#undef PRIO1
#undef PRIO0
}

// ---------------- BN2 finalize from per-block partials ----------------
__global__ __launch_bounds__(256) void k_stats2_final(
    const float* __restrict__ p2s, const float* __restrict__ p2q,
    const float* __restrict__ g2, const float* __restrict__ b2,
    float* __restrict__ a2, float* __restrict__ c2) {
  int c = blockIdx.x * 256 + threadIdx.x;
  float s = 0, q = 0;
  for (int b = 0; b < 64; ++b) {
    s += p2s[(size_t)b * NCOL1 + c];
    q += p2q[(size_t)b * NCOL1 + c];
  }
  float mean = s * (1.0f / B_N);
  float var = q * (1.0f / B_N) - mean * mean;
  float rstd = rsqrtf(var + EPS);
  float aa = rstd * g2[c];
  a2[c] = aa;
  c2[c] = b2[c] - mean * aa;
}

// ---------------- GEMM2 fused: out2 = sigmoid(G1*a2+c2) @ W2b^T ----------
// Epilogue also emits BN3 per-block column partial sums (s,q) from f32 acc.
__global__ __launch_bounds__(256) void k_gemm2(
    const __bf16* __restrict__ G1, const __bf16* __restrict__ W2b,
    const float* __restrict__ a2, const float* __restrict__ c2,
    float* __restrict__ out2, float* __restrict__ p3s,
    float* __restrict__ p3q) {
  __shared__ float sred[2][4][2][16];  // [s|q][wave][n][cc]
  const int tid = threadIdx.x;
  const int wave = tid >> 6, lane = tid & 63;
  const int m0 = blockIdx.x * 64;
  const int d = blockIdx.y;
  const int fr = lane & 15, fk = (lane >> 4) * 8;
  const __bf16* Arow = G1 + (size_t)(m0 + wave * 16 + fr) * NCOL1 + d * F_N;
  const __bf16* Wd = W2b + (size_t)d * O_N * F_N;
  const float* ap = a2 + d * F_N;
  const float* cp = c2 + d * F_N;
  f32x4 acc[2] = {};
#pragma unroll 2
  for (int k0 = 0; k0 < F_N; k0 += 32) {
    bf16x8 av = *(const bf16x8*)(Arow + k0 + fk);
    f32x4 aa0 = *(const f32x4*)(ap + k0 + fk);
    f32x4 aa1 = *(const f32x4*)(ap + k0 + fk + 4);
    f32x4 cc0 = *(const f32x4*)(cp + k0 + fk);
    f32x4 cc1 = *(const f32x4*)(cp + k0 + fk + 4);
    bf16x8 af;
#pragma unroll
    for (int j = 0; j < 4; ++j) {
      float v = (float)av[j] * aa0[j] + cc0[j];
      af[j] = (__bf16)(1.0f / (1.0f + __expf(-v)));
    }
#pragma unroll
    for (int j = 0; j < 4; ++j) {
      float v = (float)av[4 + j] * aa1[j] + cc1[j];
      af[4 + j] = (__bf16)(1.0f / (1.0f + __expf(-v)));
    }
    bf16x8 b0 = *(const bf16x8*)(Wd + (size_t)fr * F_N + k0 + fk);
    bf16x8 b1 = *(const bf16x8*)(Wd + (size_t)(16 + fr) * F_N + k0 + fk);
    acc[0] = __builtin_amdgcn_mfma_f32_16x16x32_bf16(af, b0, acc[0], 0, 0, 0);
    acc[1] = __builtin_amdgcn_mfma_f32_16x16x32_bf16(af, b1, acc[1], 0, 0, 0);
  }
  const int cr = (lane >> 4) * 4, cc = lane & 15;
#pragma unroll
  for (int n = 0; n < 2; ++n)
#pragma unroll
    for (int r = 0; r < 4; ++r)
      out2[(size_t)(m0 + wave * 16 + cr + r) * NCOL2 + d * O_N + n * 16 + cc] =
          acc[n][r];

  // ---- BN3 partial sums over this block's 64 rows, its 32 cols ----
#pragma unroll
  for (int n = 0; n < 2; ++n) {
    float s = acc[n][0] + acc[n][1] + acc[n][2] + acc[n][3];
    float q = acc[n][0] * acc[n][0] + acc[n][1] * acc[n][1] +
              acc[n][2] * acc[n][2] + acc[n][3] * acc[n][3];
    s += __shfl_xor(s, 16); s += __shfl_xor(s, 32);
    q += __shfl_xor(q, 16); q += __shfl_xor(q, 32);
    if (lane < 16) {
      sred[0][wave][n][lane] = s;
      sred[1][wave][n][lane] = q;
    }
  }
  __syncthreads();
  if (tid < 32) {
    int n = tid >> 4, c = tid & 15;
    float S = sred[0][0][n][c] + sred[0][1][n][c] + sred[0][2][n][c] +
              sred[0][3][n][c];
    float Q = sred[1][0][n][c] + sred[1][1][n][c] + sred[1][2][n][c] +
              sred[1][3][n][c];
    int col = d * O_N + n * 16 + c;
    p3s[(size_t)blockIdx.x * NCOL2 + col] = S;
    p3q[(size_t)blockIdx.x * NCOL2 + col] = Q;
  }
}

// ---------------- BN3 finalize ----------------
__global__ __launch_bounds__(128) void k_stats3_final(
    const float* __restrict__ p3s, const float* __restrict__ p3q,
    const float* __restrict__ g3, const float* __restrict__ b3,
    float* __restrict__ a3, float* __restrict__ c3) {
  int c = threadIdx.x;
  float s = 0, q = 0;
  for (int b = 0; b < 256; ++b) {
    s += p3s[(size_t)b * NCOL2 + c];
    q += p3q[(size_t)b * NCOL2 + c];
  }
  float mean = s * (1.0f / B_N);
  float var = q * (1.0f / B_N) - mean * mean;
  float rstd = rsqrtf(var + EPS);
  float aa = rstd * g3[c];
  a3[c] = aa;
  c3[c] = b3[c] - mean * aa;
}

// ---------------- final: out = sigmoid(out2*a3+c3) ----------------
__global__ __launch_bounds__(256) void k_final(const float* __restrict__ out2,
                                               const float* __restrict__ a3,
                                               const float* __restrict__ c3,
                                               float* __restrict__ out) {
  size_t base = (size_t)(blockIdx.x * 256 + threadIdx.x) * 4;
  int c = (int)(base & (NCOL2 - 1));
  f32x4 v = *(const f32x4*)(out2 + base);
  f32x4 a = *(const f32x4*)(a3 + c);
  f32x4 cc = *(const f32x4*)(c3 + c);
  f32x4 o;
#pragma unroll
  for (int j = 0; j < 4; ++j)
    o[j] = 1.0f / (1.0f + __expf(-(v[j] * a[j] + cc[j])));
  *(f32x4*)(out + base) = o;
}

extern "C" void kernel_launch(void* const* d_in, const int* in_sizes, int n_in,
                              void* d_out, int out_size, void* d_ws,
                              size_t ws_size, hipStream_t stream) {
  (void)in_sizes; (void)n_in; (void)out_size; (void)ws_size;
  const float* x = (const float*)d_in[0];
  const float* W1 = (const float*)d_in[1];
  const float* W2 = (const float*)d_in[2];
  const float* g1 = (const float*)d_in[3];
  // d_in[4] = b1: per-column constant after GEMM1, annihilated by BN2 mean-sub.
  const float* g2 = (const float*)d_in[5];
  const float* b2 = (const float*)d_in[6];
  const float* g3 = (const float*)d_in[7];
  const float* b3 = (const float*)d_in[8];
  float* out = (float*)d_out;

  char* ws = (char*)d_ws;
  size_t off = 0;
  auto alloc = [&](size_t bytes) -> void* {
    void* p = ws + off;
    off = (off + bytes + 255) & ~(size_t)255;
    return p;
  };
  float* rstdx = (float*)alloc((size_t)F_N * 4);
  float* a2 = (float*)alloc((size_t)NCOL1 * 4);
  float* c2 = (float*)alloc((size_t)NCOL1 * 4);
  float* a3 = (float*)alloc((size_t)NCOL2 * 4);
  float* c3 = (float*)alloc((size_t)NCOL2 * 4);
  float* part1 = (float*)alloc((size_t)512 * 2048 * 4);
  float* p2s = (float*)alloc((size_t)64 * NCOL1 * 4);
  float* p2q = (float*)alloc((size_t)64 * NCOL1 * 4);
  float* p3s = (float*)alloc((size_t)256 * NCOL2 * 4);
  float* p3q = (float*)alloc((size_t)256 * NCOL2 * 4);
  __bf16* W1b = (__bf16*)alloc((size_t)D_N * F_N * F_N * 2);
  __bf16* W2b = (__bf16*)alloc((size_t)D_N * O_N * F_N * 2);
  __bf16* xb = (__bf16*)alloc((size_t)B_N * F_N * 2);
  __bf16* G1 = (__bf16*)alloc((size_t)B_N * NCOL1 * 2);
  float* out2 = (float*)alloc((size_t)B_N * NCOL2 * 4);

  k_pre<<<640, 256, 0, stream>>>(x, part1, xb, W2, W2b);
  k_stats_x_final<<<4, 256, 0, stream>>>(part1, rstdx);
  k_fold_w1<<<4096, 256, 0, stream>>>(W1, g1, rstdx, W1b);
  k_gemm1<<<1024, 512, 0, stream>>>(xb, W1b, G1, p2s, p2q);
  k_stats2_final<<<16, 256, 0, stream>>>(p2s, p2q, g2, b2, a2, c2);
  k_gemm2<<<dim3(256, 4), 256, 0, stream>>>(G1, W2b, a2, c2, out2, p3s, p3q);
  k_stats3_final<<<1, 128, 0, stream>>>(p3s, p3q, g3, b3, a3, c3);
  k_final<<<2048, 256, 0, stream>>>(out2, a3, c3, out);
}

// Round 9
// 267.549 us; speedup vs baseline: 1.0741x; 1.0741x over previous
//
#include <hip/hip_runtime.h>
#include <hip/hip_bf16.h>
#include <stdint.h>

#define B_N 16384
#define F_N 1024
#define D_N 4
#define O_N 32
#define NCOL1 (D_N * F_N) /* 4096 */
#define NCOL2 (D_N * O_N) /* 128  */

static constexpr float EPS = 1e-5f;

typedef __bf16 bf16x8 __attribute__((ext_vector_type(8)));
typedef __bf16 bf16x4 __attribute__((ext_vector_type(4)));
typedef float  f32x4  __attribute__((ext_vector_type(4)));

// global -> LDS async copy, 16B per lane. LDS dest must be wave-uniform base.
#define GLD16(gp, lp)                                                          \
  __builtin_amdgcn_global_load_lds(                                            \
      (__attribute__((address_space(1))) void*)(uintptr_t)(gp),                \
      (__attribute__((address_space(3))) void*)(lp), 16, 0, 0)

// ---------------- BN1 stats on x + convert x->bf16 (fused, one pass) -------
__global__ __launch_bounds__(256) void k_stats_x_conv(
    const float* __restrict__ x, float* __restrict__ part,
    __bf16* __restrict__ xb) {
  int t = threadIdx.x, blk = blockIdx.x;
  const float4* xr = (const float4*)x;
  float s0 = 0, s1 = 0, s2 = 0, s3 = 0, q0 = 0, q1 = 0, q2 = 0, q3 = 0;
  int r0 = blk * 64;
  for (int r = r0; r < r0 + 64; ++r) {
    float4 v = xr[(size_t)r * (F_N / 4) + t];
    s0 += v.x; q0 += v.x * v.x;
    s1 += v.y; q1 += v.y * v.y;
    s2 += v.z; q2 += v.z * v.z;
    s3 += v.w; q3 += v.w * v.w;
    bf16x4 o;
    o[0] = (__bf16)v.x; o[1] = (__bf16)v.y; o[2] = (__bf16)v.z; o[3] = (__bf16)v.w;
    *(bf16x4*)(xb + (size_t)r * F_N + t * 4) = o;
  }
  float* p = part + (size_t)blk * 2048;
  p[t * 4 + 0] = s0; p[t * 4 + 1] = s1; p[t * 4 + 2] = s2; p[t * 4 + 3] = s3;
  p[1024 + t * 4 + 0] = q0; p[1024 + t * 4 + 1] = q1;
  p[1024 + t * 4 + 2] = q2; p[1024 + t * 4 + 3] = q3;
}

__global__ __launch_bounds__(256) void k_stats_x_final(
    const float* __restrict__ part, float* __restrict__ rstdx) {
  int c = blockIdx.x * 256 + threadIdx.x;
  float s = 0, q = 0;
  for (int b = 0; b < 256; ++b) {
    s += part[(size_t)b * 2048 + c];
    q += part[(size_t)b * 2048 + 1024 + c];
  }
  float mean = s * (1.0f / B_N);
  float var = q * (1.0f / B_N) - mean * mean;
  rstdx[c] = rsqrtf(var + EPS);
}

// ---------------- fold g1 * rstd1 into W1, convert to bf16 ----------------
__global__ __launch_bounds__(256) void k_fold_w1(const float* __restrict__ W1,
                                                 const float* __restrict__ g1,
                                                 const float* __restrict__ rstdx,
                                                 __bf16* __restrict__ W1b) {
  size_t base = (size_t)(blockIdx.x * 256 + threadIdx.x) * 4;
  int f = (int)(base & (F_N - 1));
  int d = (int)(base >> 20);
  float4 w = *(const float4*)(W1 + base);
  float4 g = *(const float4*)(g1 + d * F_N + f);
  float4 r = *(const float4*)(rstdx + f);
  bf16x4 o;
  o[0] = (__bf16)(w.x * g.x * r.x); o[1] = (__bf16)(w.y * g.y * r.y);
  o[2] = (__bf16)(w.z * g.z * r.z); o[3] = (__bf16)(w.w * g.w * r.w);
  *(bf16x4*)(W1b + base) = o;
}

__global__ __launch_bounds__(256) void k_fold_w2(const float* __restrict__ W2,
                                                 __bf16* __restrict__ W2b) {
  size_t base = (size_t)(blockIdx.x * 256 + threadIdx.x) * 4;
  float4 w = *(const float4*)(W2 + base);
  bf16x4 o;
  o[0] = (__bf16)w.x; o[1] = (__bf16)w.y; o[2] = (__bf16)w.z; o[3] = (__bf16)w.w;
  *(bf16x4*)(W2b + base) = o;
}

// ---------------- GEMM1: G1[16384][4096] = xb @ W1b^T, 256^2 pipelined -----
// (r4 winner, verbatim) BM=BN=256, BK=64, 8 waves, 128 KiB LDS, swizzled
// slots, XCD remap, 1-phase register pipeline (E/O frag sets), counted
// vmcnt(4) at phases 2 & 4. Epilogue: C write + BN2 column partial sums.
__global__ __launch_bounds__(512, 2) void k_gemm1(
    const __bf16* __restrict__ A, const __bf16* __restrict__ Bw,
    __bf16* __restrict__ C, float* __restrict__ p2s, float* __restrict__ p2q) {
  __shared__ __bf16 ldsA[2][2][256 * 32];
  __shared__ __bf16 ldsB[2][2][256 * 32];
  const int tid = threadIdx.x;
  const int wave = tid >> 6, lane = tid & 63;
  const int wm = wave >> 2, wn = wave & 3;
  int bid = (int)blockIdx.x;
  const int c_ = bid & 7, q_ = bid >> 3;
  const int bm = c_ * 8 + (q_ >> 4), bn = q_ & 15;
  const int m0 = bm * 256, n0 = bn * 256;
  const int fr = lane & 15, kg = lane >> 4;
  const int swz8 = (kg ^ ((fr >> 1) & 3)) * 8;
  const int srow = tid >> 2;
  const int scb = ((tid & 3) ^ ((tid >> 3) & 3)) * 16;
  const char* Ab = (const char*)A + (size_t)(m0 + srow) * (F_N * 2) + scb;
  const char* Bb = (const char*)Bw + (size_t)(n0 + srow) * (F_N * 2) + scb;
  char* ldsAx = (char*)&ldsA[0][0][0];
  char* ldsBx = (char*)&ldsB[0][0][0];
  const int wo = wave * 1024;

#define SA(buf_, kk_, kb_)                                                     \
  do {                                                                         \
    GLD16(Ab + (kb_) + (kk_) * 64,                                             \
          ldsAx + (buf_) * 32768 + (kk_) * 16384 + wo);                        \
    GLD16(Ab + 128 * (F_N * 2) + (kb_) + (kk_) * 64,                           \
          ldsAx + (buf_) * 32768 + (kk_) * 16384 + 8192 + wo);                 \
  } while (0)
#define SBv(buf_, kk_, kb_)                                                    \
  do {                                                                         \
    GLD16(Bb + (kb_) + (kk_) * 64,                                             \
          ldsBx + (buf_) * 32768 + (kk_) * 16384 + wo);                        \
    GLD16(Bb + 128 * (F_N * 2) + (kb_) + (kk_) * 64,                           \
          ldsBx + (buf_) * 32768 + (kk_) * 16384 + 8192 + wo);                 \
  } while (0)
#define LDA4(dst_, buf_, kk_, qm_)                                             \
  { _Pragma("unroll") for (int i_ = 0; i_ < 4; ++i_)                           \
      dst_[i_] = *(const bf16x8*)&ldsA[buf_][kk_]                              \
          [(wm * 128 + (qm_) * 64 + i_ * 16 + fr) * 32 + swz8]; }
#define LDB4(dst_, buf_, kk_)                                                  \
  { _Pragma("unroll") for (int i_ = 0; i_ < 4; ++i_)                           \
      dst_[i_] = *(const bf16x8*)&ldsB[buf_][kk_]                              \
          [(wn * 64 + i_ * 16 + fr) * 32 + swz8]; }
#define MFMA16(a_, b_, qm_)                                                    \
  { _Pragma("unroll") for (int i_ = 0; i_ < 4; ++i_)                           \
      _Pragma("unroll") for (int j_ = 0; j_ < 4; ++j_)                         \
        acc[(qm_) * 4 + i_][j_] = __builtin_amdgcn_mfma_f32_16x16x32_bf16(     \
            a_[i_], b_[j_], acc[(qm_) * 4 + i_][j_], 0, 0, 0); }
#define BAR() __builtin_amdgcn_s_barrier()
#define SB0() __builtin_amdgcn_sched_barrier(0)
#define WAITVM4() asm volatile("s_waitcnt vmcnt(4)" ::: "memory")
#define PRIO1() __builtin_amdgcn_s_setprio(1)
#define PRIO0() __builtin_amdgcn_s_setprio(0)

  f32x4 acc[8][4] = {};
  bf16x8 afrE[4], afrO[4], bfrE[4], bfrO[4];

  SBv(0, 0, 0); SA(0, 0, 0); SBv(0, 1, 0); SA(0, 1, 0);
  asm volatile("s_waitcnt vmcnt(4)" ::: "memory");
  BAR(); SB0();
  LDA4(afrE, 0, 0, 0); LDB4(bfrE, 0, 0);

#define TILE(b_, nb_, kn_)                                                     \
  SBv(nb_, 0, kn_); BAR(); SB0();                                              \
  LDA4(afrO, b_, 0, 1);                                                        \
  PRIO1(); MFMA16(afrE, bfrE, 0); PRIO0();                                     \
  SA(nb_, 0, kn_); WAITVM4(); BAR(); SB0();                                    \
  LDA4(afrE, b_, 1, 0); LDB4(bfrO, b_, 1);                                     \
  PRIO1(); MFMA16(afrO, bfrE, 1); PRIO0();                                     \
  SBv(nb_, 1, kn_); BAR(); SB0();                                              \
  LDA4(afrO, b_, 1, 1);                                                        \
  PRIO1(); MFMA16(afrE, bfrO, 0); PRIO0();                                     \
  SA(nb_, 1, kn_); WAITVM4(); BAR(); SB0();                                    \
  LDA4(afrE, nb_, 0, 0); LDB4(bfrE, nb_, 0);                                   \
  PRIO1(); MFMA16(afrO, bfrO, 1); PRIO0();

  for (int t = 0; t < 16; t += 2) {
    const int kn1 = (t + 1) * 128;
    const int kn2 = (t + 2 < 16) ? (t + 2) * 128 : 0;  // tail wraps (harmless)
    TILE(0, 1, kn1)
    TILE(1, 0, kn2)
  }

  // ---- epilogue: C write ----
  const int cr = kg * 4, cc = fr;
#pragma unroll
  for (int mi = 0; mi < 8; ++mi)
#pragma unroll
    for (int ni = 0; ni < 4; ++ni) {
      int row = m0 + wm * 128 + mi * 16 + cr;
      int col = n0 + wn * 64 + ni * 16 + cc;
#pragma unroll
      for (int r = 0; r < 4; ++r)
        C[(size_t)(row + r) * NCOL1 + col] = (__bf16)acc[mi][ni][r];
    }

  // ---- epilogue: BN2 per-block column partial sums (from f32 acc) ----
  float* srs = (float*)&ldsA[1][0][0];
  float* srq = srs + 512;
  __syncthreads();
#pragma unroll
  for (int ni = 0; ni < 4; ++ni) {
    float ss = 0, qq = 0;
#pragma unroll
    for (int mi = 0; mi < 8; ++mi) {
      f32x4 v = acc[mi][ni];
#pragma unroll
      for (int r = 0; r < 4; ++r) { ss += v[r]; qq += v[r] * v[r]; }
    }
    ss += __shfl_xor(ss, 16); ss += __shfl_xor(ss, 32);
    qq += __shfl_xor(qq, 16); qq += __shfl_xor(qq, 32);
    if (lane < 16) {
      srs[wave * 64 + ni * 16 + lane] = ss;
      srq[wave * 64 + ni * 16 + lane] = qq;
    }
  }
  __syncthreads();
  if (tid < 256) {
    int j = tid, wnn = j >> 6, jj = j & 63;
    float S = srs[wnn * 64 + jj] + srs[(4 + wnn) * 64 + jj];
    float Q = srq[wnn * 64 + jj] + srq[(4 + wnn) * 64 + jj];
    p2s[(size_t)bm * NCOL1 + n0 + j] = S;
    p2q[(size_t)bm * NCOL1 + n0 + j] = Q;
  }
#undef SA
#undef SBv
#undef LDA4
#undef LDB4
#undef MFMA16
#undef TILE
#undef BAR
#undef SB0
#undef WAITVM4
#undef PRIO1
#undef PRIO0
}

// ---------------- BN2 finalize from per-block partials ----------------
__global__ __launch_bounds__(256) void k_stats2_final(
    const float* __restrict__ p2s, const float* __restrict__ p2q,
    const float* __restrict__ g2, const float* __restrict__ b2,
    float* __restrict__ a2, float* __restrict__ c2) {
  int c = blockIdx.x * 256 + threadIdx.x;
  float s = 0, q = 0;
  for (int b = 0; b < 64; ++b) {
    s += p2s[(size_t)b * NCOL1 + c];
    q += p2q[(size_t)b * NCOL1 + c];
  }
  float mean = s * (1.0f / B_N);
  float var = q * (1.0f / B_N) - mean * mean;
  float rstd = rsqrtf(var + EPS);
  float aa = rstd * g2[c];
  a2[c] = aa;
  c2[c] = b2[c] - mean * aa;
}

// ---------------- GEMM2 fused: out2 = sigmoid(G1*a2+c2) @ W2b^T ----------
// Epilogue also emits BN3 per-block column partial sums (s,q) from f32 acc.
__global__ __launch_bounds__(256) void k_gemm2(
    const __bf16* __restrict__ G1, const __bf16* __restrict__ W2b,
    const float* __restrict__ a2, const float* __restrict__ c2,
    float* __restrict__ out2, float* __restrict__ p3s,
    float* __restrict__ p3q) {
  __shared__ float sred[2][4][2][16];  // [s|q][wave][n][cc]
  const int tid = threadIdx.x;
  const int wave = tid >> 6, lane = tid & 63;
  const int m0 = blockIdx.x * 64;
  const int d = blockIdx.y;
  const int fr = lane & 15, fk = (lane >> 4) * 8;
  const __bf16* Arow = G1 + (size_t)(m0 + wave * 16 + fr) * NCOL1 + d * F_N;
  const __bf16* Wd = W2b + (size_t)d * O_N * F_N;
  const float* ap = a2 + d * F_N;
  const float* cp = c2 + d * F_N;
  f32x4 acc[2] = {};
#pragma unroll 2
  for (int k0 = 0; k0 < F_N; k0 += 32) {
    bf16x8 av = *(const bf16x8*)(Arow + k0 + fk);
    f32x4 aa0 = *(const f32x4*)(ap + k0 + fk);
    f32x4 aa1 = *(const f32x4*)(ap + k0 + fk + 4);
    f32x4 cc0 = *(const f32x4*)(cp + k0 + fk);
    f32x4 cc1 = *(const f32x4*)(cp + k0 + fk + 4);
    bf16x8 af;
#pragma unroll
    for (int j = 0; j < 4; ++j) {
      float v = (float)av[j] * aa0[j] + cc0[j];
      af[j] = (__bf16)(1.0f / (1.0f + __expf(-v)));
    }
#pragma unroll
    for (int j = 0; j < 4; ++j) {
      float v = (float)av[4 + j] * aa1[j] + cc1[j];
      af[4 + j] = (__bf16)(1.0f / (1.0f + __expf(-v)));
    }
    bf16x8 b0 = *(const bf16x8*)(Wd + (size_t)fr * F_N + k0 + fk);
    bf16x8 b1 = *(const bf16x8*)(Wd + (size_t)(16 + fr) * F_N + k0 + fk);
    acc[0] = __builtin_amdgcn_mfma_f32_16x16x32_bf16(af, b0, acc[0], 0, 0, 0);
    acc[1] = __builtin_amdgcn_mfma_f32_16x16x32_bf16(af, b1, acc[1], 0, 0, 0);
  }
  const int cr = (lane >> 4) * 4, cc = lane & 15;
#pragma unroll
  for (int n = 0; n < 2; ++n)
#pragma unroll
    for (int r = 0; r < 4; ++r)
      out2[(size_t)(m0 + wave * 16 + cr + r) * NCOL2 + d * O_N + n * 16 + cc] =
          acc[n][r];

  // ---- BN3 partial sums over this block's 64 rows, its 32 cols ----
#pragma unroll
  for (int n = 0; n < 2; ++n) {
    float s = acc[n][0] + acc[n][1] + acc[n][2] + acc[n][3];
    float q = acc[n][0] * acc[n][0] + acc[n][1] * acc[n][1] +
              acc[n][2] * acc[n][2] + acc[n][3] * acc[n][3];
    s += __shfl_xor(s, 16); s += __shfl_xor(s, 32);
    q += __shfl_xor(q, 16); q += __shfl_xor(q, 32);
    if (lane < 16) {
      sred[0][wave][n][lane] = s;
      sred[1][wave][n][lane] = q;
    }
  }
  __syncthreads();
  if (tid < 32) {
    int n = tid >> 4, c = tid & 15;
    float S = sred[0][0][n][c] + sred[0][1][n][c] + sred[0][2][n][c] +
              sred[0][3][n][c];
    float Q = sred[1][0][n][c] + sred[1][1][n][c] + sred[1][2][n][c] +
              sred[1][3][n][c];
    int col = d * O_N + n * 16 + c;
    p3s[(size_t)blockIdx.x * NCOL2 + col] = S;
    p3q[(size_t)blockIdx.x * NCOL2 + col] = Q;
  }
}

// ---------------- BN3 finalize ----------------
__global__ __launch_bounds__(128) void k_stats3_final(
    const float* __restrict__ p3s, const float* __restrict__ p3q,
    const float* __restrict__ g3, const float* __restrict__ b3,
    float* __restrict__ a3, float* __restrict__ c3) {
  int c = threadIdx.x;
  float s = 0, q = 0;
  for (int b = 0; b < 256; ++b) {
    s += p3s[(size_t)b * NCOL2 + c];
    q += p3q[(size_t)b * NCOL2 + c];
  }
  float mean = s * (1.0f / B_N);
  float var = q * (1.0f / B_N) - mean * mean;
  float rstd = rsqrtf(var + EPS);
  float aa = rstd * g3[c];
  a3[c] = aa;
  c3[c] = b3[c] - mean * aa;
}

// ---------------- final: out = sigmoid(out2*a3+c3) ----------------
__global__ __launch_bounds__(256) void k_final(const float* __restrict__ out2,
                                               const float* __restrict__ a3,
                                               const float* __restrict__ c3,
                                               float* __restrict__ out) {
  size_t base = (size_t)(blockIdx.x * 256 + threadIdx.x) * 4;
  int c = (int)(base & (NCOL2 - 1));
  f32x4 v = *(const f32x4*)(out2 + base);
  f32x4 a = *(const f32x4*)(a3 + c);
  f32x4 cc = *(const f32x4*)(c3 + c);
  f32x4 o;
#pragma unroll
  for (int j = 0; j < 4; ++j)
    o[j] = 1.0f / (1.0f + __expf(-(v[j] * a[j] + cc[j])));
  *(f32x4*)(out + base) = o;
}

extern "C" void kernel_launch(void* const* d_in, const int* in_sizes, int n_in,
                              void* d_out, int out_size, void* d_ws,
                              size_t ws_size, hipStream_t stream) {
  (void)in_sizes; (void)n_in; (void)out_size; (void)ws_size;
  const float* x = (const float*)d_in[0];
  const float* W1 = (const float*)d_in[1];
  const float* W2 = (const float*)d_in[2];
  const float* g1 = (const float*)d_in[3];
  // d_in[4] = b1: per-column constant after GEMM1, annihilated by BN2 mean-sub.
  const float* g2 = (const float*)d_in[5];
  const float* b2 = (const float*)d_in[6];
  const float* g3 = (const float*)d_in[7];
  const float* b3 = (const float*)d_in[8];
  float* out = (float*)d_out;

  char* ws = (char*)d_ws;
  size_t off = 0;
  auto alloc = [&](size_t bytes) -> void* {
    void* p = ws + off;
    off = (off + bytes + 255) & ~(size_t)255;
    return p;
  };
  float* rstdx = (float*)alloc((size_t)F_N * 4);
  float* a2 = (float*)alloc((size_t)NCOL1 * 4);
  float* c2 = (float*)alloc((size_t)NCOL1 * 4);
  float* a3 = (float*)alloc((size_t)NCOL2 * 4);
  float* c3 = (float*)alloc((size_t)NCOL2 * 4);
  float* part1 = (float*)alloc((size_t)256 * 2048 * 4);
  float* p2s = (float*)alloc((size_t)64 * NCOL1 * 4);
  float* p2q = (float*)alloc((size_t)64 * NCOL1 * 4);
  float* p3s = (float*)alloc((size_t)256 * NCOL2 * 4);
  float* p3q = (float*)alloc((size_t)256 * NCOL2 * 4);
  __bf16* W1b = (__bf16*)alloc((size_t)D_N * F_N * F_N * 2);
  __bf16* W2b = (__bf16*)alloc((size_t)D_N * O_N * F_N * 2);
  __bf16* xb = (__bf16*)alloc((size_t)B_N * F_N * 2);
  __bf16* G1 = (__bf16*)alloc((size_t)B_N * NCOL1 * 2);
  float* out2 = (float*)alloc((size_t)B_N * NCOL2 * 4);

  k_stats_x_conv<<<256, 256, 0, stream>>>(x, part1, xb);
  k_stats_x_final<<<4, 256, 0, stream>>>(part1, rstdx);
  k_fold_w1<<<4096, 256, 0, stream>>>(W1, g1, rstdx, W1b);
  k_fold_w2<<<128, 256, 0, stream>>>(W2, W2b);
  k_gemm1<<<1024, 512, 0, stream>>>(xb, W1b, G1, p2s, p2q);
  k_stats2_final<<<16, 256, 0, stream>>>(p2s, p2q, g2, b2, a2, c2);
  k_gemm2<<<dim3(256, 4), 256, 0, stream>>>(G1, W2b, a2, c2, out2, p3s, p3q);
  k_stats3_final<<<1, 128, 0, stream>>>(p3s, p3q, g3, b3, a3, c3);
  k_final<<<2048, 256, 0, stream>>>(out2, a3, c3, out);
}